// Round 12
// baseline (160.565 us; speedup 1.0000x reference)
//
#include <hip/hip_runtime.h>

#define BATCH 256
#define IN1   10240
#define NU    32
#define NB    32              // batches per block (R1 structure)
#define BGROUPS (BATCH / NB)  // 8
#define SPLITS 128
#define STRIPE (IN1 / SPLITS) // 80 i per block = 40 pairs = 5 rounds x 8 il
#define LOG2E 1.4426950408889634f

// ---------------- Kernel 0: pack transformed params -----------------------
// Ppk[i*32+u] = {A, C, W, W*erev};  A = iw*ssig*log2e, C = (smu-ib)*ssig*log2e
__global__ __launch_bounds__(256) void ltc_pack(
    const float* __restrict__ iw, const float* __restrict__ ibias,
    const float* __restrict__ smu, const float* __restrict__ ssig,
    const float* __restrict__ sW, const float* __restrict__ serev,
    float4* __restrict__ Ppk)
{
    const int idx = blockIdx.x * 256 + threadIdx.x;   // 0..IN1*NU-1
    const int i = idx >> 5;
    const float sg = ssig[idx] * LOG2E;
    const float A  = sg * iw[i];
    const float C  = (smu[idx] - ibias[i]) * sg;
    const float w  = sW[idx];
    Ppk[idx] = make_float4(A, C, w, w * serev[idx]);
}

// ---------------- Kernel 1: sensory partial sums (PAIR algebra) -----------
// R1's 29us structure: thread = (u = tid&31, il = tid>>5); 32 batches in
// register accumulators; x broadcast-loaded per (n, i-pair) as float2.
// NEW: consecutive-i pair combining -- ONE v_rcp serves 2 tasks and both
// accumulators:  w0*s0 + w1*s1 = (w01 + w0*e1 + w1*e0) / ((1+e0)(1+e1)).
// Trans ops/task drop 2 -> 1.5 (the measured ~26us trans-unit wall -> ~19).
// t clamped at 30 so D01 <= 2^62 (no overflow; sigma error < 2^-30).
__global__ __launch_bounds__(256, 4) void ltc_sensory_partial(
    const float* __restrict__ x,
    const float4* __restrict__ Ppk,
    float2* __restrict__ part)
{
    const int tid = threadIdx.x;
    const int u   = tid & 31;
    const int il  = tid >> 5;          // 0..7: pair-slice
    const int w   = tid >> 6;          // wave 0..3
    const int b0  = blockIdx.x * NB;
    const int i0  = blockIdx.y * STRIPE;

    float2 acc[NB];                    // {num, den} per batch
#pragma unroll
    for (int n = 0; n < NB; ++n) acc[n] = make_float2(0.f, 0.f);

    for (int rnd = 0; rnd < STRIPE / 16; ++rnd) {
        const int pi = i0 + (rnd * 8 + il) * 2;        // even i of the pair
        const float4 P0 = Ppk[(size_t)pi * NU + u];    // {A0,C0,w0,we0}
        const float4 P1 = Ppk[(size_t)(pi + 1) * NU + u];
        const float w01  = P0.z + P1.z;
        const float we01 = P0.w + P1.w;
        const float* xp = x + pi;
#pragma unroll
        for (int n = 0; n < NB; ++n) {
            const float2 xv = *(const float2*)(xp + (size_t)(b0 + n) * IN1);
            const float t0 = fminf(30.f, P0.y - xv.x * P0.x);
            const float t1 = fminf(30.f, P1.y - xv.y * P1.x);
            const float e0 = __builtin_amdgcn_exp2f(t0);
            const float e1 = __builtin_amdgcn_exp2f(t1);
            const float D  = (1.0f + e0) * (1.0f + e1);
            const float rD = __builtin_amdgcn_rcpf(D);
            const float numN = fmaf(P1.w, e0, fmaf(P0.w, e1, we01));
            const float numD = fmaf(P1.z, e0, fmaf(P0.z, e1, w01));
            acc[n].x = fmaf(numN, rD, acc[n].x);
            acc[n].y = fmaf(numD, rD, acc[n].y);
        }
    }

    // deterministic reduction over il (8 slices spread across 4 waves)
    __shared__ float wred[4][NB][NU][2];   // 32 KB
#pragma unroll
    for (int n = 0; n < NB; ++n) {
        const float vn = acc[n].x + __shfl_xor(acc[n].x, 32, 64);
        const float vd = acc[n].y + __shfl_xor(acc[n].y, 32, 64);
        if ((tid & 63) < 32) {
            wred[w][n][u][0] = vn;
            wred[w][n][u][1] = vd;
        }
    }
    __syncthreads();
    for (int p = tid; p < NB * NU; p += 256) {
        const int n = p >> 5, uu = p & 31;
        const float sn = wred[0][n][uu][0] + wred[1][n][uu][0]
                       + wred[2][n][uu][0] + wred[3][n][uu][0];
        const float sd = wred[0][n][uu][1] + wred[1][n][uu][1]
                       + wred[2][n][uu][1] + wred[3][n][uu][1];
        part[((size_t)blockIdx.y * BATCH + (b0 + n)) * NU + uu] =
            make_float2(sn, sd);
    }
}

// ---------------- Kernel 2: reduce split partials -------------------------
__global__ __launch_bounds__(256) void ltc_reduce(
    const float2* __restrict__ part, int nsplit, float2* __restrict__ S)
{
    const int tid = threadIdx.x;
    const int b   = blockIdx.x;
    const int u   = tid & 31;
    const int sl  = tid >> 5;

    __shared__ float sred[8][NU][2];

    float sn = 0.f, sd = 0.f;
#pragma unroll 8
    for (int s = sl; s < nsplit; s += 8) {
        const float2 p = part[((size_t)s * BATCH + b) * NU + u];
        sn += p.x;
        sd += p.y;
    }
    sred[sl][u][0] = sn;
    sred[sl][u][1] = sd;
    __syncthreads();

    if (tid >= 32) return;
    float Sn = 0.f, Sd = 0.f;
#pragma unroll
    for (int s2 = 0; s2 < 8; ++s2) {
        Sn += sred[s2][u][0];
        Sd += sred[s2][u][1];
    }
    S[(size_t)b * NU + u] = make_float2(Sn, Sd);
}

// ---------------- Kernel 3: unfolds + cell B + output ---------------------
__global__ __launch_bounds__(256) void ltc_unfold(
    const float2* __restrict__ S,
    const float* __restrict__ amu, const float* __restrict__ asig,
    const float* __restrict__ aW,  const float* __restrict__ aerev,
    const float* __restrict__ agleak, const float* __restrict__ avleak,
    const float* __restrict__ acm,
    const float* __restrict__ b_iw, const float* __restrict__ b_ib,
    const float* __restrict__ b_smu, const float* __restrict__ b_ssig,
    const float* __restrict__ b_sW,  const float* __restrict__ b_serev,
    const float* __restrict__ b_mu,  const float* __restrict__ b_sig,
    const float* __restrict__ b_W,   const float* __restrict__ b_erev,
    const float* __restrict__ b_gleak, const float* __restrict__ b_vleak,
    const float* __restrict__ b_cm,
    float* __restrict__ out)
{
    const int tid = threadIdx.x;
    const int u   = tid & 31;
    const int bl  = tid >> 5;
    const int b   = blockIdx.x * 8 + bl;

    __shared__ float pAp[NU*NU], pCp[NU*NU];
    __shared__ float pW[NU*NU],  pWE[NU*NU];

    for (int p = tid; p < NU * NU; p += 256) {
        const float sg = asig[p] * LOG2E;
        pAp[p] = sg;
        pCp[p] = amu[p] * sg;
        const float w = aW[p];
        pW[p]  = w;
        pWE[p] = w * aerev[p];
    }
    __syncthreads();

    const float2 Sv = S[(size_t)b * NU + u];
    const float Sn = Sv.x, Sd = Sv.y;

    const float cmt = acm[u] * 6.0f;
    const float gl  = agleak[u];
    const float gv  = gl * avleak[u];

    float v = 0.f;
    for (int k = 0; k < 6; ++k) {
        float rn = 0.f, rd = 0.f;
#pragma unroll
        for (int j = 0; j < NU; ++j) {
            const float vj = __shfl(v, j, 32);
            const int pi = j * NU + u;
            const float e = __builtin_amdgcn_exp2f(pCp[pi] - vj * pAp[pi]);
            const float r = __builtin_amdgcn_rcpf(1.0f + e);
            rn = fmaf(pWE[pi], r, rn);
            rd = fmaf(pW[pi],  r, rd);
        }
        const float num = cmt * v + gv + rn + Sn;
        const float den = cmt + gl + rd + Sd;
        v = num / den;
    }

    const float x2  = v * b_iw[u] + b_ib[u];
    const float e2  = __builtin_amdgcn_exp2f((b_smu[u] - x2) * b_ssig[u] * LOG2E);
    const float s2v = b_sW[u] * __builtin_amdgcn_rcpf(1.0f + e2);
    float wn = s2v * b_serev[u];
    float wd = s2v;
#pragma unroll
    for (int m = 16; m >= 1; m >>= 1) {
        wn += __shfl_xor(wn, m, 32);
        wd += __shfl_xor(wd, m, 32);
    }

    const float bcmt = b_cm[0] * 6.0f;
    const float bgl  = b_gleak[0];
    const float bgv  = bgl * b_vleak[0];
    const float bmu  = b_mu[0], bsig = b_sig[0], bW = b_W[0], berev = b_erev[0];
    float v2 = 0.f;
#pragma unroll
    for (int k = 0; k < 6; ++k) {
        const float ee = __builtin_amdgcn_exp2f((bmu - v2) * bsig * LOG2E);
        const float ws = bW * __builtin_amdgcn_rcpf(1.0f + ee);
        const float num = bcmt * v2 + bgv + ws * berev + wn;
        const float den = bcmt + bgl + ws + wd;
        v2 = num / den;
    }

    if (u == 0)
        out[b] = 1.0f / (1.0f + __builtin_amdgcn_exp2f(-v2 * LOG2E));
}

extern "C" void kernel_launch(void* const* d_in, const int* in_sizes, int n_in,
                              void* d_out, int out_size, void* d_ws, size_t ws_size,
                              hipStream_t stream) {
    const float* x       = (const float*)d_in[0];
    const float* a_iw    = (const float*)d_in[1];
    const float* a_ib    = (const float*)d_in[2];
    const float* a_smu   = (const float*)d_in[3];
    const float* a_ssig  = (const float*)d_in[4];
    const float* a_sW    = (const float*)d_in[5];
    const float* a_serev = (const float*)d_in[6];
    const float* a_mu    = (const float*)d_in[7];
    const float* a_sig   = (const float*)d_in[8];
    const float* a_W     = (const float*)d_in[9];
    const float* a_erev  = (const float*)d_in[10];
    const float* a_gleak = (const float*)d_in[11];
    const float* a_vleak = (const float*)d_in[12];
    const float* a_cm    = (const float*)d_in[13];
    const float* b_iw    = (const float*)d_in[14];
    const float* b_ib    = (const float*)d_in[15];
    const float* b_smu   = (const float*)d_in[16];
    const float* b_ssig  = (const float*)d_in[17];
    const float* b_sW    = (const float*)d_in[18];
    const float* b_serev = (const float*)d_in[19];
    const float* b_mu    = (const float*)d_in[20];
    const float* b_sig   = (const float*)d_in[21];
    const float* b_W     = (const float*)d_in[22];
    const float* b_erev  = (const float*)d_in[23];
    const float* b_gleak = (const float*)d_in[24];
    const float* b_vleak = (const float*)d_in[25];
    const float* b_cm    = (const float*)d_in[26];
    float* out = (float*)d_out;

    float4* Ppk  = (float4*)d_ws;                                // 5.24 MB
    float2* part = (float2*)(Ppk + (size_t)IN1 * NU);            // 8.39 MB
    float2* Sarr = part + (size_t)SPLITS * BATCH * NU;           // 64 KB

    ltc_pack<<<(IN1 * NU) / 256, 256, 0, stream>>>(
        a_iw, a_ib, a_smu, a_ssig, a_sW, a_serev, Ppk);

    dim3 g1(BGROUPS, SPLITS);
    ltc_sensory_partial<<<g1, 256, 0, stream>>>(x, Ppk, part);

    ltc_reduce<<<BATCH, 256, 0, stream>>>(part, SPLITS, Sarr);

    ltc_unfold<<<BATCH / 8, 256, 0, stream>>>(
        Sarr,
        a_mu, a_sig, a_W, a_erev, a_gleak, a_vleak, a_cm,
        b_iw, b_ib, b_smu, b_ssig, b_sW, b_serev,
        b_mu, b_sig, b_W, b_erev, b_gleak, b_vleak, b_cm,
        out);
}